// Round 14
// baseline (158.001 us; speedup 1.0000x reference)
//
#include <hip/hip_runtime.h>

#define FDIM 128
#define NBMAX 128     // max dst-buckets per graph (N<=65536 -> <=128 buckets of 512)
#define CAPB 10240    // per-bucket capacity in binned[] (E/NB ~ 8163, 23 sigma slack)

typedef short short8 __attribute__((ext_vector_type(8)));
typedef float f32x4 __attribute__((ext_vector_type(4)));

static __device__ __forceinline__ unsigned short f2bf(float f) {
    unsigned u = __float_as_uint(f);
    u += 0x7FFF + ((u >> 16) & 1);          // round-to-nearest-even
    return (unsigned short)(u >> 16);
}
static __device__ __forceinline__ float bf2f(unsigned short h) {
    return __uint_as_float(((unsigned)h) << 16);
}

// ---------------- pack weights + zero gCnt (40 blocks; runs before binconv) ----------
__global__ __launch_bounds__(256) void pack_kernel(
    int* __restrict__ gCnt, int nb3,
    const float* __restrict__ Wl1, const float* __restrict__ Wr1,
    const float* __restrict__ Wl2, const float* __restrict__ Wr2,
    const float* __restrict__ Wl3, const float* __restrict__ Wr3,
    ushort* __restrict__ Wp1, ushort* __restrict__ Wp2, ushort* __restrict__ Wp3)
{
    int b = blockIdx.x;
    if (b == 0) {
        for (int k = threadIdx.x; k < nb3; k += 256) gCnt[k] = 0;
    }
    if (b < 32) {
        const float *Wl, *Wr; ushort* Wp; int base;
        if (b < 16) { Wl = Wl1; Wr = Wr1; Wp = Wp1; base = b; }
        else        { Wl = Wl2; Wr = Wr2; Wp = Wp2; base = b - 16; }
        int idx = base * 256 + threadIdx.x;          // < 8*8*64 = 4096
        int lane = idx & 63;
        int jt = (idx >> 6) % 8;
        int kt = (idx >> 6) / 8;
        int kbase = kt * 32 + (lane >> 4) * 8;
        int j = jt * 16 + (lane & 15);
        const float* W = (kbase < 128) ? Wl : Wr;
        int kb = kbase & 127;
        ushort tmp[8];
#pragma unroll
        for (int t = 0; t < 8; ++t) tmp[t] = f2bf(W[(size_t)(kb + t) * 128 + j]);
        *reinterpret_cast<uint4*>(Wp + (size_t)idx * 8) = *reinterpret_cast<uint4*>(tmp);
        return;
    }
    // layer 3: K=128, FOUT=128 = [Wl3 (64 cols) | Wr3 (64 cols)]
    int idx = (b - 32) * 256 + threadIdx.x;          // < 4*8*64 = 2048
    if (idx >= 4 * 8 * 64) return;
    int lane = idx & 63;
    int jt = (idx >> 6) % 8;
    int kt = (idx >> 6) / 8;                         // 0..3
    int kbase = kt * 32 + (lane >> 4) * 8;
    int j = jt * 16 + (lane & 15);
    const float* W = (j < 64) ? Wl3 : Wr3;
    int jj = j & 63;
    ushort tmp[8];
#pragma unroll
    for (int t = 0; t < 8; ++t) tmp[t] = f2bf(W[(size_t)(kbase + t) * 64 + jj]);
    *reinterpret_cast<uint4*>(Wp3 + (size_t)idx * 8) = *reinterpret_cast<uint4*>(tmp);
}

// ---------------- binconv: blocks 0..3*bpg-1 bin edges; rest convert x -> bf16 --------
__global__ __launch_bounds__(256) void binconv_kernel(
    const int* __restrict__ ei1, const int* __restrict__ ei2, const int* __restrict__ ei3,
    int* __restrict__ gCnt, unsigned* __restrict__ binned,
    int E, int NB, int bpg,
    const float* __restrict__ x, ushort* __restrict__ xb, int n4)
{
    __shared__ int hist[NBMAX];
    __shared__ int excl[NBMAX];
    __shared__ int cursor[NBMAX];
    __shared__ int gbase[NBMAX];
    __shared__ unsigned stag[4096];

    const int nbin = 3 * bpg;
    if ((int)blockIdx.x >= nbin) {
        int i = (blockIdx.x - nbin) * 256 + threadIdx.x;
        if (i >= n4) return;
        float4 v = reinterpret_cast<const float4*>(x)[i];
        ushort4 o = { f2bf(v.x), f2bf(v.y), f2bf(v.z), f2bf(v.w) };
        reinterpret_cast<ushort4*>(xb)[i] = o;
        return;
    }
    const int g = blockIdx.x / bpg;
    const int c = blockIdx.x % bpg;
    const int* ei = (g == 0) ? ei1 : (g == 1) ? ei2 : ei3;
    const int e0 = c * 4096;
    const int chunk = min(4096, E - e0);
    const int t = threadIdx.x;

    if (t < NB) hist[t] = 0;
    __syncthreads();
    for (int i = t; i < chunk; i += 256)
        atomicAdd(&hist[ei[E + e0 + i] >> 9], 1);
    __syncthreads();
    if (t < 64) {
        int a = (2 * t     < NB) ? hist[2 * t]     : 0;
        int b = (2 * t + 1 < NB) ? hist[2 * t + 1] : 0;
        int s = a + b, incl = s;
#pragma unroll
        for (int d = 1; d < 64; d <<= 1) {
            int x2 = __shfl_up(incl, d);
            if (t >= d) incl += x2;
        }
        int ex = incl - s;
        if (2 * t     < NB) { excl[2 * t]     = ex;     cursor[2 * t]     = ex; }
        if (2 * t + 1 < NB) { excl[2 * t + 1] = ex + a; cursor[2 * t + 1] = ex + a; }
    }
    __syncthreads();
    if (t < NB) {
        int cnt = hist[t];
        gbase[t] = cnt ? atomicAdd(&gCnt[g * NB + t], cnt) : 0;
    }
    __syncthreads();
    for (int i = t; i < chunk; i += 256) {
        int src = ei[e0 + i];
        int dst = ei[E + e0 + i];
        int pl = atomicAdd(&cursor[dst >> 9], 1);
        stag[pl] = ((unsigned)dst << 16) | (unsigned)src;
    }
    __syncthreads();
    for (int i = t; i < chunk; i += 256) {
        unsigned u = stag[i];
        int bk = u >> 25;
        int off = gbase[bk] + (i - excl[bk]);
        if (off < CAPB)
            binned[(size_t)(g * NB + bk) * CAPB + off] = u;
    }
}

// ---------------- per-bucket CSR fill (computes its own global scan) ----------------
__global__ __launch_bounds__(256) void fill2_kernel(
    const unsigned* __restrict__ binned, const int* __restrict__ gCnt,
    int* __restrict__ rowptr, ushort* __restrict__ colu, int N, int NB)
{
    __shared__ int hist[512];
    __shared__ int cursor[512];
    __shared__ int wsum[4];
    __shared__ int sColBase, sTotal;

    const int M = 3 * NB;
    const int gb = blockIdx.x;
    const int g = gb / NB, b = gb % NB;
    const int t = threadIdx.x;
    const int lane = t & 63, w = t >> 6;

    {
        int v0 = (2 * t     < M) ? gCnt[2 * t]     : 0;
        int v1 = (2 * t + 1 < M) ? gCnt[2 * t + 1] : 0;
        int s2 = v0 + v1, incl = s2;
#pragma unroll
        for (int d = 1; d < 64; d <<= 1) {
            int x = __shfl_up(incl, d);
            if (lane >= d) incl += x;
        }
        if (lane == 63) wsum[w] = incl;
        __syncthreads();
        int woff = 0;
        for (int ww = 0; ww < w; ++ww) woff += wsum[ww];
        int ex = woff + incl - s2;
        if (2 * t     == gb) sColBase = ex;
        if (2 * t + 1 == gb) sColBase = ex + v0;
        if (2 * t     == M - 1) sTotal = ex + v0;
        if (2 * t + 1 == M - 1) sTotal = ex + v0 + v1;
        __syncthreads();
    }
    const int colBase = sColBase;
    if (gb == 0 && t == 0) rowptr[(size_t)3 * N] = sTotal;

    const int n0 = b << 9;
    const int NL = min(512, N - n0);
    const int cnt = min(gCnt[gb], CAPB);
    const size_t ebase = (size_t)gb * CAPB;

    __syncthreads();
    hist[t] = 0; hist[t + 256] = 0;
    __syncthreads();
    for (int e = t; e < cnt; e += 256)
        atomicAdd(&hist[(binned[ebase + e] >> 16) & 511], 1);
    __syncthreads();
    int a = hist[2 * t], bb = hist[2 * t + 1];
    int s2 = a + bb, incl = s2;
#pragma unroll
    for (int d = 1; d < 64; d <<= 1) {
        int x = __shfl_up(incl, d);
        if (lane >= d) incl += x;
    }
    if (lane == 63) wsum[w] = incl;
    __syncthreads();
    int woff = 0;
    for (int ww = 0; ww < w; ++ww) woff += wsum[ww];
    int ex = woff + incl - s2;
    if (2 * t     < NL) rowptr[(size_t)g * N + n0 + 2 * t]     = colBase + ex;
    if (2 * t + 1 < NL) rowptr[(size_t)g * N + n0 + 2 * t + 1] = colBase + ex + a;
    cursor[2 * t] = ex; cursor[2 * t + 1] = ex + a;
    __syncthreads();
    for (int e = t; e < cnt; e += 256) {
        unsigned u = binned[ebase + e];
        int pl = atomicAdd(&cursor[(u >> 16) & 511], 1);
        colu[colBase + pl] = (ushort)(u & 0xFFFFu);
    }
}

static __device__ __forceinline__ float4 unpk_lo(uint4 v) {
    return make_float4(__uint_as_float(v.x << 16), __uint_as_float(v.x & 0xFFFF0000u),
                       __uint_as_float(v.y << 16), __uint_as_float(v.y & 0xFFFF0000u));
}
static __device__ __forceinline__ float4 unpk_hi(uint4 v) {
    return make_float4(__uint_as_float(v.z << 16), __uint_as_float(v.z & 0xFFFF0000u),
                       __uint_as_float(v.w << 16), __uint_as_float(v.w & 0xFFFF0000u));
}

// ---- software-pipelined masked 8-edge batches (SHIFT: log2 of row width in ushorts) ----
struct B8 { uint4 v[8]; };

template<int SHIFT>
static __device__ __forceinline__ void issue8(
    const ushort* __restrict__ src, const ushort* __restrict__ col,
    int e, int last, int l, B8& b)
{
#pragma unroll
    for (int i = 0; i < 8; ++i) {
        int idx = min(e + i, last);
        b.v[i] = *reinterpret_cast<const uint4*>(src + ((size_t)col[idx] << SHIFT) + l * 8);
    }
}
static __device__ __forceinline__ void accum8(
    const B8& b, int e, int last, float4& a0, float4& a1)
{
#pragma unroll
    for (int i = 0; i < 8; ++i) {
        float m = (e + i <= last) ? 1.f : 0.f;
        a0 += unpk_lo(b.v[i]) * m;
        a1 += unpk_hi(b.v[i]) * m;
    }
}

// pipelined gather core: sums rows col[beg..end) chunk l; returns raw sums in a0,a1
template<int SHIFT>
static __device__ __forceinline__ void gather_sum(
    const ushort* __restrict__ src, const ushort* __restrict__ col,
    int beg, int end, int l, float4& a0, float4& a1)
{
    a0 = make_float4(0.f, 0.f, 0.f, 0.f);
    a1 = make_float4(0.f, 0.f, 0.f, 0.f);
    int e = beg, last = end - 1;
    if (e > last) return;
    B8 A, Bb;
    int eA = e;
    issue8<SHIFT>(src, col, eA, last, l, A);
    e += 8;
    bool done = false;
    while (e <= last) {
        int eB = e;
        issue8<SHIFT>(src, col, eB, last, l, Bb);
        accum8(A, eA, last, a0, a1);
        e += 8;
        if (e > last) { accum8(Bb, eB, last, a0, a1); done = true; break; }
        eA = e;
        issue8<SHIFT>(src, col, eA, last, l, A);
        accum8(Bb, eB, last, a0, a1);
        e += 8;
    }
    if (!done) accum8(A, eA, last, a0, a1);
}

// gather one node's mean into a uint4 (bf16x8) for feature chunk l (16 lanes/node)
static __device__ __forceinline__ uint4 gather_mean(
    const ushort* __restrict__ src, const int* __restrict__ rp,
    const ushort* __restrict__ col, int n, int l)
{
    int beg = rp[n], end = rp[n + 1];
    float4 a0, a1;
    gather_sum<7>(src, col, beg, end, l, a0, a1);
    int deg = end - beg;
    float inv = 1.0f / (float)(deg > 1 ? deg : 1);
    uint4 o;
    o.x = (unsigned)f2bf(a0.x * inv) | ((unsigned)f2bf(a0.y * inv) << 16);
    o.y = (unsigned)f2bf(a0.z * inv) | ((unsigned)f2bf(a0.w * inv) << 16);
    o.z = (unsigned)f2bf(a1.x * inv) | ((unsigned)f2bf(a1.y * inv) << 16);
    o.w = (unsigned)f2bf(a1.z * inv) | ((unsigned)f2bf(a1.w * inv) << 16);
    return o;
}

// ---------------- fused layer 1: gather mean1 -> LDS, stage x self -> LDS,
//                  hb = relu([mean||x]@[Wl;Wr] + b1)   (16 nodes/block) ----------------
__global__ __launch_bounds__(256) void fused_l1(
    const ushort* __restrict__ xb, const int* __restrict__ rp,
    const ushort* __restrict__ col, const ushort* __restrict__ Wp,
    const float* __restrict__ bias, ushort* __restrict__ hb, int N)
{
    __shared__ __align__(16) ushort sA[16 * 256];   // 16 rows x 32 slots(16B), swizzled
    const int tid = threadIdx.x;
    const int grp = tid >> 4;          // row 0..15
    const int l = tid & 15;            // feature chunk
    const int n0 = blockIdx.x * 16;
    int n = n0 + grp; if (n >= N) n = N - 1;

    // mean -> slot l (issue pipeline first: it's the critical path)
    {
        uint4 o = gather_mean(xb, rp, col, n, l);
        int sp = (l & 24) | ((l ^ grp) & 7);
        *reinterpret_cast<uint4*>(&sA[(grp << 8) + (sp << 3)]) = o;
    }
    // self row -> slot 16+l
    {
        uint4 v = *reinterpret_cast<const uint4*>(xb + ((size_t)n << 7) + l * 8);
        int s = 16 + l;
        int sp = (s & 24) | ((s ^ grp) & 7);
        *reinterpret_cast<uint4*>(&sA[(grp << 8) + (sp << 3)]) = v;
    }
    __syncthreads();

    const int lane = tid & 63;
    const int w = tid >> 6;
    const int rloc = lane & 15;
    const int q = lane >> 4;

    f32x4 acc[2];
    acc[0] = (f32x4){0.f, 0.f, 0.f, 0.f};
    acc[1] = (f32x4){0.f, 0.f, 0.f, 0.f};
#pragma unroll
    for (int kt = 0; kt < 8; ++kt) {
        int s = kt * 4 + q;
        int sp = (s & 24) | ((s ^ rloc) & 7);
        short8 a = *reinterpret_cast<const short8*>(&sA[(rloc << 8) + (sp << 3)]);
#pragma unroll
        for (int jj = 0; jj < 2; ++jj) {
            int jt = w * 2 + jj;
            short8 b = *reinterpret_cast<const short8*>(Wp + ((size_t)((kt * 8 + jt) * 64 + lane) << 3));
            acc[jj] = __builtin_amdgcn_mfma_f32_16x16x32_bf16(a, b, acc[jj], 0, 0, 0);
        }
    }

#pragma unroll
    for (int jj = 0; jj < 2; ++jj) {
        int j = (w * 2 + jj) * 16 + (lane & 15);
        float bj = bias[j];
#pragma unroll
        for (int reg = 0; reg < 4; ++reg) {
            int nn = n0 + q * 4 + reg;
            if (nn < N)
                hb[((size_t)nn << 7) + j] = f2bf(fmaxf(acc[jj][reg] + bj, 0.f));
        }
    }
}

// ---------------- fused layers 2+3: gather mean2 -> LDS, stage hb self -> LDS,
//   h2 = relu([mean2||hb]@W2 + b2) + hb (LDS only), [y3|z3] = h2@[Wl3|Wr3] ----------------
__global__ __launch_bounds__(256) void fused_l23(
    const ushort* __restrict__ hb, const int* __restrict__ rp,
    const ushort* __restrict__ col,
    const ushort* __restrict__ Wp2, const float* __restrict__ b2,
    const ushort* __restrict__ Wp3, const float* __restrict__ b3,
    ushort* __restrict__ y3, float* __restrict__ out, int N)
{
    __shared__ __align__(16) ushort sA[16 * 256];    // [mean2 || hb_self], swizzled
    __shared__ __align__(16) ushort sH[16 * 128];    // h2, swizzled (16 slots)
    const int tid = threadIdx.x;
    const int grp = tid >> 4;
    const int l = tid & 15;
    const int n0 = blockIdx.x * 16;
    int n = n0 + grp; if (n >= N) n = N - 1;

    {
        uint4 o = gather_mean(hb, rp, col, n, l);
        int sp = (l & 24) | ((l ^ grp) & 7);
        *reinterpret_cast<uint4*>(&sA[(grp << 8) + (sp << 3)]) = o;
    }
    {
        uint4 v = *reinterpret_cast<const uint4*>(hb + ((size_t)n << 7) + l * 8);
        int s = 16 + l;
        int sp = (s & 24) | ((s ^ grp) & 7);
        *reinterpret_cast<uint4*>(&sA[(grp << 8) + (sp << 3)]) = v;
    }
    __syncthreads();

    const int lane = tid & 63;
    const int w = tid >> 6;
    const int rloc = lane & 15;
    const int q = lane >> 4;

    // ---- layer-2 MFMA (K=256) ----
    f32x4 acc[2];
    acc[0] = (f32x4){0.f, 0.f, 0.f, 0.f};
    acc[1] = (f32x4){0.f, 0.f, 0.f, 0.f};
#pragma unroll
    for (int kt = 0; kt < 8; ++kt) {
        int s = kt * 4 + q;
        int sp = (s & 24) | ((s ^ rloc) & 7);
        short8 a = *reinterpret_cast<const short8*>(&sA[(rloc << 8) + (sp << 3)]);
#pragma unroll
        for (int jj = 0; jj < 2; ++jj) {
            int jt = w * 2 + jj;
            short8 b = *reinterpret_cast<const short8*>(Wp2 + ((size_t)((kt * 8 + jt) * 64 + lane) << 3));
            acc[jj] = __builtin_amdgcn_mfma_f32_16x16x32_bf16(a, b, acc[jj], 0, 0, 0);
        }
    }

    // ---- epilogue 2: h2 = relu(acc + b2) + hb_self (from sA), write bf16 to sH ----
#pragma unroll
    for (int jj = 0; jj < 2; ++jj) {
        int j = (w * 2 + jj) * 16 + (lane & 15);
        float bj = b2[j];
        int sSelf = 16 + (j >> 3);
        int s = j >> 3;                               // h2 slot 0..15
#pragma unroll
        for (int reg = 0; reg < 4; ++reg) {
            int r = q * 4 + reg;
            int spSelf = (sSelf & 24) | ((sSelf ^ r) & 7);
            float hself = bf2f(sA[(r << 8) + (spSelf << 3) + (j & 7)]);
            float v = fmaxf(acc[jj][reg] + bj, 0.f) + hself;
            int sp = (s & 8) | ((s ^ r) & 7);
            sH[(r << 7) + (sp << 3) + (j & 7)] = f2bf(v);
        }
    }
    __syncthreads();

    // ---- layer-3 MFMA (K=128) ----
    acc[0] = (f32x4){0.f, 0.f, 0.f, 0.f};
    acc[1] = (f32x4){0.f, 0.f, 0.f, 0.f};
#pragma unroll
    for (int kt = 0; kt < 4; ++kt) {
        int s = kt * 4 + q;
        int sp = (s & 8) | ((s ^ rloc) & 7);
        short8 a = *reinterpret_cast<const short8*>(&sH[(rloc << 7) + (sp << 3)]);
#pragma unroll
        for (int jj = 0; jj < 2; ++jj) {
            int jt = w * 2 + jj;
            short8 b = *reinterpret_cast<const short8*>(Wp3 + ((size_t)((kt * 8 + jt) * 64 + lane) << 3));
            acc[jj] = __builtin_amdgcn_mfma_f32_16x16x32_bf16(a, b, acc[jj], 0, 0, 0);
        }
    }

    // ---- epilogue 3: jt<4 -> y3 bf16; jt>=4 -> out = z3 + b3 fp32 ----
#pragma unroll
    for (int jj = 0; jj < 2; ++jj) {
        int jt = w * 2 + jj;
        int j = jt * 16 + (lane & 15);
#pragma unroll
        for (int reg = 0; reg < 4; ++reg) {
            int nn = n0 + q * 4 + reg;
            if (nn < N) {
                if (jt < 4) {
                    y3[((size_t)nn << 6) + j] = f2bf(acc[jj][reg]);
                } else {
                    out[((size_t)nn << 6) + (j - 64)] = acc[jj][reg] + b3[j - 64];
                }
            }
        }
    }
}

// ---------------- gather3: out[n] += mean over edges of y3[col[e]] (64-wide rows) ----
__global__ __launch_bounds__(256) void gather3_kernel(
    const ushort* __restrict__ y3, const int* __restrict__ rp,
    const ushort* __restrict__ col, float* __restrict__ out, int N)
{
    int node = blockIdx.x * 32 + (threadIdx.x >> 3);
    if (node >= N) return;
    int l = threadIdx.x & 7;
    int beg = rp[node], end = rp[node + 1];
    float4 a0, a1;
    gather_sum<6>(y3, col, beg, end, l, a0, a1);

    int deg = end - beg;
    float inv = 1.0f / (float)(deg > 1 ? deg : 1);
    float* po = out + ((size_t)node << 6) + l * 8;
    float4 o0 = *reinterpret_cast<const float4*>(po);
    float4 o1 = *reinterpret_cast<const float4*>(po + 4);
    o0.x += a0.x * inv; o0.y += a0.y * inv; o0.z += a0.z * inv; o0.w += a0.w * inv;
    o1.x += a1.x * inv; o1.y += a1.y * inv; o1.z += a1.z * inv; o1.w += a1.w * inv;
    *reinterpret_cast<float4*>(po)     = o0;
    *reinterpret_cast<float4*>(po + 4) = o1;
}

extern "C" void kernel_launch(void* const* d_in, const int* in_sizes, int n_in,
                              void* d_out, int out_size, void* d_ws, size_t ws_size,
                              hipStream_t stream) {
    const float* x   = (const float*)d_in[0];
    const int*   ei1 = (const int*)d_in[1];
    const int*   ei2 = (const int*)d_in[2];
    const int*   ei3 = (const int*)d_in[3];
    const float* Wl1 = (const float*)d_in[4];
    const float* Wr1 = (const float*)d_in[5];
    const float* b1  = (const float*)d_in[6];
    const float* Wl2 = (const float*)d_in[7];
    const float* Wr2 = (const float*)d_in[8];
    const float* b2  = (const float*)d_in[9];
    const float* Wl3 = (const float*)d_in[10];
    const float* Wr3 = (const float*)d_in[11];
    const float* b3  = (const float*)d_in[12];
    float* out = (float*)d_out;

    const int N = in_sizes[0] / FDIM;   // 50000
    const int E = in_sizes[1] / 2;      // 800000
    const int NB = (N + 511) >> 9;      // 98 buckets of 512 nodes

    auto al = [](size_t v) { return (v + 255) & ~(size_t)255; };
    char* ws = (char*)d_ws;
    ushort* xb   = (ushort*)ws;   ws += al((size_t)N * FDIM * 2);
    ushort* hb   = (ushort*)ws;   ws += al((size_t)N * FDIM * 2);
    ushort* y3   = (ushort*)ws;   ws += al((size_t)N * 64 * 2);
    ushort* Wp1  = (ushort*)ws;   ws += al((size_t)8 * 8 * 64 * 8 * 2);
    ushort* Wp2  = (ushort*)ws;   ws += al((size_t)8 * 8 * 64 * 8 * 2);
    ushort* Wp3  = (ushort*)ws;   ws += al((size_t)4 * 8 * 64 * 8 * 2);
    int*     rowptr = (int*)ws;   ws += al((size_t)(3 * N + 1) * 4);
    int*     gCnt   = (int*)ws;   ws += al((size_t)(3 * NB) * 4);
    unsigned* binned = (unsigned*)ws; ws += al((size_t)3 * NB * CAPB * 4);
    ushort*  colu   = (ushort*)ws;

    const int bpg = (E + 4095) / 4096;
    const int n4  = N * FDIM / 4;
    const int fusedBlocks   = (N + 15) / 16;
    const int gather3Blocks = (N + 31) / 32;

    // pack weights + zero gCnt (stream-ordered before binconv's atomics)
    pack_kernel<<<40, 256, 0, stream>>>(
        gCnt, 3 * NB, Wl1, Wr1, Wl2, Wr2, Wl3, Wr3, Wp1, Wp2, Wp3);

    // bin (blocks 0..3*bpg-1) overlapped with x->bf16 convert (remaining blocks)
    binconv_kernel<<<3 * bpg + (n4 + 255) / 256, 256, 0, stream>>>(
        ei1, ei2, ei3, gCnt, binned, E, NB, bpg, x, xb, n4);

    // per-bucket CSR fill (self-scanning)
    fill2_kernel<<<3 * NB, 256, 0, stream>>>(binned, gCnt, rowptr, colu, N, NB);

    // fused layer 1: gather + GEMM
    fused_l1<<<fusedBlocks, 256, 0, stream>>>(xb, rowptr, colu, Wp1, b1, hb, N);

    // fused layers 2+3: gather + GEMM2 + GEMM3 (h2 via LDS)
    fused_l23<<<fusedBlocks, 256, 0, stream>>>(
        hb, rowptr + N, colu, Wp2, b2, Wp3, b3, y3, out, N);

    // out += mean3(y3)
    gather3_kernel<<<gather3Blocks, 256, 0, stream>>>(y3, rowptr + 2 * N, colu, out, N);
}

// Round 15
// 145.433 us; speedup vs baseline: 1.0864x; 1.0864x over previous
//
#include <hip/hip_runtime.h>

#define FDIM 128
#define NBMAX 128     // max dst-buckets per graph (N<=65536 -> <=128 buckets of 512)
#define CAPB 10240    // per-bucket capacity in binned[] (E/NB ~ 8163, 23 sigma slack)

typedef short short8 __attribute__((ext_vector_type(8)));
typedef float f32x4 __attribute__((ext_vector_type(4)));

static __device__ __forceinline__ unsigned short f2bf(float f) {
    unsigned u = __float_as_uint(f);
    u += 0x7FFF + ((u >> 16) & 1);          // round-to-nearest-even
    return (unsigned short)(u >> 16);
}
static __device__ __forceinline__ float bf2f(unsigned short h) {
    return __uint_as_float(((unsigned)h) << 16);
}

// ---------------- pack weights + zero gCnt (40 blocks; runs before binconv) ----------
__global__ __launch_bounds__(256) void pack_kernel(
    int* __restrict__ gCnt, int nb3,
    const float* __restrict__ Wl1, const float* __restrict__ Wr1,
    const float* __restrict__ Wl2, const float* __restrict__ Wr2,
    const float* __restrict__ Wl3, const float* __restrict__ Wr3,
    ushort* __restrict__ Wp1, ushort* __restrict__ Wp2, ushort* __restrict__ Wp3)
{
    int b = blockIdx.x;
    if (b == 0) {
        for (int k = threadIdx.x; k < nb3; k += 256) gCnt[k] = 0;
    }
    if (b < 32) {
        const float *Wl, *Wr; ushort* Wp; int base;
        if (b < 16) { Wl = Wl1; Wr = Wr1; Wp = Wp1; base = b; }
        else        { Wl = Wl2; Wr = Wr2; Wp = Wp2; base = b - 16; }
        int idx = base * 256 + threadIdx.x;          // < 8*8*64 = 4096
        int lane = idx & 63;
        int jt = (idx >> 6) % 8;
        int kt = (idx >> 6) / 8;
        int kbase = kt * 32 + (lane >> 4) * 8;
        int j = jt * 16 + (lane & 15);
        const float* W = (kbase < 128) ? Wl : Wr;
        int kb = kbase & 127;
        ushort tmp[8];
#pragma unroll
        for (int t = 0; t < 8; ++t) tmp[t] = f2bf(W[(size_t)(kb + t) * 128 + j]);
        *reinterpret_cast<uint4*>(Wp + (size_t)idx * 8) = *reinterpret_cast<uint4*>(tmp);
        return;
    }
    // layer 3: K=128, FOUT=128 = [Wl3 (64 cols) | Wr3 (64 cols)]
    int idx = (b - 32) * 256 + threadIdx.x;          // < 4*8*64 = 2048
    if (idx >= 4 * 8 * 64) return;
    int lane = idx & 63;
    int jt = (idx >> 6) % 8;
    int kt = (idx >> 6) / 8;                         // 0..3
    int kbase = kt * 32 + (lane >> 4) * 8;
    int j = jt * 16 + (lane & 15);
    const float* W = (j < 64) ? Wl3 : Wr3;
    int jj = j & 63;
    ushort tmp[8];
#pragma unroll
    for (int t = 0; t < 8; ++t) tmp[t] = f2bf(W[(size_t)(kbase + t) * 64 + jj]);
    *reinterpret_cast<uint4*>(Wp3 + (size_t)idx * 8) = *reinterpret_cast<uint4*>(tmp);
}

// ---------------- binconv: blocks 0..3*bpg-1 bin edges; rest convert x -> bf16 --------
__global__ __launch_bounds__(256) void binconv_kernel(
    const int* __restrict__ ei1, const int* __restrict__ ei2, const int* __restrict__ ei3,
    int* __restrict__ gCnt, unsigned* __restrict__ binned,
    int E, int NB, int bpg,
    const float* __restrict__ x, ushort* __restrict__ xb, int n4)
{
    __shared__ int hist[NBMAX];
    __shared__ int excl[NBMAX];
    __shared__ int cursor[NBMAX];
    __shared__ int gbase[NBMAX];
    __shared__ unsigned stag[4096];

    const int nbin = 3 * bpg;
    if ((int)blockIdx.x >= nbin) {
        int i = (blockIdx.x - nbin) * 256 + threadIdx.x;
        if (i >= n4) return;
        float4 v = reinterpret_cast<const float4*>(x)[i];
        ushort4 o = { f2bf(v.x), f2bf(v.y), f2bf(v.z), f2bf(v.w) };
        reinterpret_cast<ushort4*>(xb)[i] = o;
        return;
    }
    const int g = blockIdx.x / bpg;
    const int c = blockIdx.x % bpg;
    const int* ei = (g == 0) ? ei1 : (g == 1) ? ei2 : ei3;
    const int e0 = c * 4096;
    const int chunk = min(4096, E - e0);
    const int t = threadIdx.x;

    if (t < NB) hist[t] = 0;
    __syncthreads();
    for (int i = t; i < chunk; i += 256)
        atomicAdd(&hist[ei[E + e0 + i] >> 9], 1);
    __syncthreads();
    if (t < 64) {
        int a = (2 * t     < NB) ? hist[2 * t]     : 0;
        int b = (2 * t + 1 < NB) ? hist[2 * t + 1] : 0;
        int s = a + b, incl = s;
#pragma unroll
        for (int d = 1; d < 64; d <<= 1) {
            int x2 = __shfl_up(incl, d);
            if (t >= d) incl += x2;
        }
        int ex = incl - s;
        if (2 * t     < NB) { excl[2 * t]     = ex;     cursor[2 * t]     = ex; }
        if (2 * t + 1 < NB) { excl[2 * t + 1] = ex + a; cursor[2 * t + 1] = ex + a; }
    }
    __syncthreads();
    if (t < NB) {
        int cnt = hist[t];
        gbase[t] = cnt ? atomicAdd(&gCnt[g * NB + t], cnt) : 0;
    }
    __syncthreads();
    for (int i = t; i < chunk; i += 256) {
        int src = ei[e0 + i];
        int dst = ei[E + e0 + i];
        int pl = atomicAdd(&cursor[dst >> 9], 1);
        stag[pl] = ((unsigned)dst << 16) | (unsigned)src;
    }
    __syncthreads();
    for (int i = t; i < chunk; i += 256) {
        unsigned u = stag[i];
        int bk = u >> 25;
        int off = gbase[bk] + (i - excl[bk]);
        if (off < CAPB)
            binned[(size_t)(g * NB + bk) * CAPB + off] = u;
    }
}

// ---------------- per-bucket CSR fill (computes its own global scan) ----------------
__global__ __launch_bounds__(256) void fill2_kernel(
    const unsigned* __restrict__ binned, const int* __restrict__ gCnt,
    int* __restrict__ rowptr, ushort* __restrict__ colu, int N, int NB)
{
    __shared__ int hist[512];
    __shared__ int cursor[512];
    __shared__ int wsum[4];
    __shared__ int sColBase, sTotal;

    const int M = 3 * NB;
    const int gb = blockIdx.x;
    const int g = gb / NB, b = gb % NB;
    const int t = threadIdx.x;
    const int lane = t & 63, w = t >> 6;

    {
        int v0 = (2 * t     < M) ? gCnt[2 * t]     : 0;
        int v1 = (2 * t + 1 < M) ? gCnt[2 * t + 1] : 0;
        int s2 = v0 + v1, incl = s2;
#pragma unroll
        for (int d = 1; d < 64; d <<= 1) {
            int x = __shfl_up(incl, d);
            if (lane >= d) incl += x;
        }
        if (lane == 63) wsum[w] = incl;
        __syncthreads();
        int woff = 0;
        for (int ww = 0; ww < w; ++ww) woff += wsum[ww];
        int ex = woff + incl - s2;
        if (2 * t     == gb) sColBase = ex;
        if (2 * t + 1 == gb) sColBase = ex + v0;
        if (2 * t     == M - 1) sTotal = ex + v0;
        if (2 * t + 1 == M - 1) sTotal = ex + v0 + v1;
        __syncthreads();
    }
    const int colBase = sColBase;
    if (gb == 0 && t == 0) rowptr[(size_t)3 * N] = sTotal;

    const int n0 = b << 9;
    const int NL = min(512, N - n0);
    const int cnt = min(gCnt[gb], CAPB);
    const size_t ebase = (size_t)gb * CAPB;

    __syncthreads();
    hist[t] = 0; hist[t + 256] = 0;
    __syncthreads();
    for (int e = t; e < cnt; e += 256)
        atomicAdd(&hist[(binned[ebase + e] >> 16) & 511], 1);
    __syncthreads();
    int a = hist[2 * t], bb = hist[2 * t + 1];
    int s2 = a + bb, incl = s2;
#pragma unroll
    for (int d = 1; d < 64; d <<= 1) {
        int x = __shfl_up(incl, d);
        if (lane >= d) incl += x;
    }
    if (lane == 63) wsum[w] = incl;
    __syncthreads();
    int woff = 0;
    for (int ww = 0; ww < w; ++ww) woff += wsum[ww];
    int ex = woff + incl - s2;
    if (2 * t     < NL) rowptr[(size_t)g * N + n0 + 2 * t]     = colBase + ex;
    if (2 * t + 1 < NL) rowptr[(size_t)g * N + n0 + 2 * t + 1] = colBase + ex + a;
    cursor[2 * t] = ex; cursor[2 * t + 1] = ex + a;
    __syncthreads();
    for (int e = t; e < cnt; e += 256) {
        unsigned u = binned[ebase + e];
        int pl = atomicAdd(&cursor[(u >> 16) & 511], 1);
        colu[colBase + pl] = (ushort)(u & 0xFFFFu);
    }
}

static __device__ __forceinline__ float4 unpk_lo(uint4 v) {
    return make_float4(__uint_as_float(v.x << 16), __uint_as_float(v.x & 0xFFFF0000u),
                       __uint_as_float(v.y << 16), __uint_as_float(v.y & 0xFFFF0000u));
}
static __device__ __forceinline__ float4 unpk_hi(uint4 v) {
    return make_float4(__uint_as_float(v.z << 16), __uint_as_float(v.z & 0xFFFF0000u),
                       __uint_as_float(v.w << 16), __uint_as_float(v.w & 0xFFFF0000u));
}

// gather one node's mean into a uint4 (bf16x8) for feature chunk l (16 lanes/node)
static __device__ __forceinline__ uint4 gather_mean(
    const ushort* __restrict__ src, const int* __restrict__ rp,
    const ushort* __restrict__ col, int n, int l)
{
    int beg = rp[n], end = rp[n + 1];
    float4 a0 = make_float4(0.f, 0.f, 0.f, 0.f);
    float4 a1 = make_float4(0.f, 0.f, 0.f, 0.f);
    int e = beg;
    for (; e + 8 <= end; e += 8) {
        uint4 v0 = *reinterpret_cast<const uint4*>(src + ((size_t)col[e]     << 7) + l * 8);
        uint4 v1 = *reinterpret_cast<const uint4*>(src + ((size_t)col[e + 1] << 7) + l * 8);
        uint4 v2 = *reinterpret_cast<const uint4*>(src + ((size_t)col[e + 2] << 7) + l * 8);
        uint4 v3 = *reinterpret_cast<const uint4*>(src + ((size_t)col[e + 3] << 7) + l * 8);
        uint4 v4 = *reinterpret_cast<const uint4*>(src + ((size_t)col[e + 4] << 7) + l * 8);
        uint4 v5 = *reinterpret_cast<const uint4*>(src + ((size_t)col[e + 5] << 7) + l * 8);
        uint4 v6 = *reinterpret_cast<const uint4*>(src + ((size_t)col[e + 6] << 7) + l * 8);
        uint4 v7 = *reinterpret_cast<const uint4*>(src + ((size_t)col[e + 7] << 7) + l * 8);
        a0 += unpk_lo(v0); a1 += unpk_hi(v0);
        a0 += unpk_lo(v1); a1 += unpk_hi(v1);
        a0 += unpk_lo(v2); a1 += unpk_hi(v2);
        a0 += unpk_lo(v3); a1 += unpk_hi(v3);
        a0 += unpk_lo(v4); a1 += unpk_hi(v4);
        a0 += unpk_lo(v5); a1 += unpk_hi(v5);
        a0 += unpk_lo(v6); a1 += unpk_hi(v6);
        a0 += unpk_lo(v7); a1 += unpk_hi(v7);
    }
    if (e < end) {
        int last = end - 1;
        int c0 = col[e];
        int c1 = col[min(e + 1, last)];
        int c2 = col[min(e + 2, last)];
        int c3 = col[min(e + 3, last)];
        int c4 = col[min(e + 4, last)];
        int c5 = col[min(e + 5, last)];
        int c6 = col[min(e + 6, last)];
        int c7 = col[min(e + 7, last)];
        uint4 v0 = *reinterpret_cast<const uint4*>(src + ((size_t)c0 << 7) + l * 8);
        uint4 v1 = *reinterpret_cast<const uint4*>(src + ((size_t)c1 << 7) + l * 8);
        uint4 v2 = *reinterpret_cast<const uint4*>(src + ((size_t)c2 << 7) + l * 8);
        uint4 v3 = *reinterpret_cast<const uint4*>(src + ((size_t)c3 << 7) + l * 8);
        uint4 v4 = *reinterpret_cast<const uint4*>(src + ((size_t)c4 << 7) + l * 8);
        uint4 v5 = *reinterpret_cast<const uint4*>(src + ((size_t)c5 << 7) + l * 8);
        uint4 v6 = *reinterpret_cast<const uint4*>(src + ((size_t)c6 << 7) + l * 8);
        uint4 v7 = *reinterpret_cast<const uint4*>(src + ((size_t)c7 << 7) + l * 8);
        float m1 = (e + 1 <= last) ? 1.f : 0.f;
        float m2 = (e + 2 <= last) ? 1.f : 0.f;
        float m3 = (e + 3 <= last) ? 1.f : 0.f;
        float m4 = (e + 4 <= last) ? 1.f : 0.f;
        float m5 = (e + 5 <= last) ? 1.f : 0.f;
        float m6 = (e + 6 <= last) ? 1.f : 0.f;
        float m7 = (e + 7 <= last) ? 1.f : 0.f;
        a0 += unpk_lo(v0);      a1 += unpk_hi(v0);
        a0 += unpk_lo(v1) * m1; a1 += unpk_hi(v1) * m1;
        a0 += unpk_lo(v2) * m2; a1 += unpk_hi(v2) * m2;
        a0 += unpk_lo(v3) * m3; a1 += unpk_hi(v3) * m3;
        a0 += unpk_lo(v4) * m4; a1 += unpk_hi(v4) * m4;
        a0 += unpk_lo(v5) * m5; a1 += unpk_hi(v5) * m5;
        a0 += unpk_lo(v6) * m6; a1 += unpk_hi(v6) * m6;
        a0 += unpk_lo(v7) * m7; a1 += unpk_hi(v7) * m7;
    }
    int deg = end - beg;
    float inv = 1.0f / (float)(deg > 1 ? deg : 1);
    uint4 o;
    o.x = (unsigned)f2bf(a0.x * inv) | ((unsigned)f2bf(a0.y * inv) << 16);
    o.y = (unsigned)f2bf(a0.z * inv) | ((unsigned)f2bf(a0.w * inv) << 16);
    o.z = (unsigned)f2bf(a1.x * inv) | ((unsigned)f2bf(a1.y * inv) << 16);
    o.w = (unsigned)f2bf(a1.z * inv) | ((unsigned)f2bf(a1.w * inv) << 16);
    return o;
}

// ---------------- fused layer 1: gather mean1 -> LDS, stage x self -> LDS,
//                  hb = relu([mean||x]@[Wl;Wr] + b1)   (16 nodes/block) ----------------
__global__ __launch_bounds__(256) void fused_l1(
    const ushort* __restrict__ xb, const int* __restrict__ rp,
    const ushort* __restrict__ col, const ushort* __restrict__ Wp,
    const float* __restrict__ bias, ushort* __restrict__ hb, int N)
{
    __shared__ __align__(16) ushort sA[16 * 256];   // 16 rows x 32 slots(16B), swizzled
    const int tid = threadIdx.x;
    const int grp = tid >> 4;          // row 0..15
    const int l = tid & 15;            // feature chunk
    const int n0 = blockIdx.x * 16;
    int n = n0 + grp; if (n >= N) n = N - 1;

    // self row -> slot 16+l
    {
        uint4 v = *reinterpret_cast<const uint4*>(xb + ((size_t)n << 7) + l * 8);
        int s = 16 + l;
        int sp = (s & 24) | ((s ^ grp) & 7);
        *reinterpret_cast<uint4*>(&sA[(grp << 8) + (sp << 3)]) = v;
    }
    // mean -> slot l
    {
        uint4 o = gather_mean(xb, rp, col, n, l);
        int sp = (l & 24) | ((l ^ grp) & 7);
        *reinterpret_cast<uint4*>(&sA[(grp << 8) + (sp << 3)]) = o;
    }
    __syncthreads();

    const int lane = tid & 63;
    const int w = tid >> 6;
    const int rloc = lane & 15;
    const int q = lane >> 4;

    f32x4 acc[2];
    acc[0] = (f32x4){0.f, 0.f, 0.f, 0.f};
    acc[1] = (f32x4){0.f, 0.f, 0.f, 0.f};
#pragma unroll
    for (int kt = 0; kt < 8; ++kt) {
        int s = kt * 4 + q;
        int sp = (s & 24) | ((s ^ rloc) & 7);
        short8 a = *reinterpret_cast<const short8*>(&sA[(rloc << 8) + (sp << 3)]);
#pragma unroll
        for (int jj = 0; jj < 2; ++jj) {
            int jt = w * 2 + jj;
            short8 b = *reinterpret_cast<const short8*>(Wp + ((size_t)((kt * 8 + jt) * 64 + lane) << 3));
            acc[jj] = __builtin_amdgcn_mfma_f32_16x16x32_bf16(a, b, acc[jj], 0, 0, 0);
        }
    }

#pragma unroll
    for (int jj = 0; jj < 2; ++jj) {
        int j = (w * 2 + jj) * 16 + (lane & 15);
        float bj = bias[j];
#pragma unroll
        for (int reg = 0; reg < 4; ++reg) {
            int nn = n0 + q * 4 + reg;
            if (nn < N)
                hb[((size_t)nn << 7) + j] = f2bf(fmaxf(acc[jj][reg] + bj, 0.f));
        }
    }
}

// ---------------- fused layers 2+3: gather mean2 -> LDS, stage hb self -> LDS,
//   h2 = relu([mean2||hb]@W2 + b2) + hb (LDS only), [y3|z3] = h2@[Wl3|Wr3] ----------------
__global__ __launch_bounds__(256) void fused_l23(
    const ushort* __restrict__ hb, const int* __restrict__ rp,
    const ushort* __restrict__ col,
    const ushort* __restrict__ Wp2, const float* __restrict__ b2,
    const ushort* __restrict__ Wp3, const float* __restrict__ b3,
    ushort* __restrict__ y3, float* __restrict__ out, int N)
{
    __shared__ __align__(16) ushort sA[16 * 256];    // [mean2 || hb_self], swizzled
    __shared__ __align__(16) ushort sH[16 * 128];    // h2, swizzled (16 slots)
    const int tid = threadIdx.x;
    const int grp = tid >> 4;
    const int l = tid & 15;
    const int n0 = blockIdx.x * 16;
    int n = n0 + grp; if (n >= N) n = N - 1;

    {
        uint4 v = *reinterpret_cast<const uint4*>(hb + ((size_t)n << 7) + l * 8);
        int s = 16 + l;
        int sp = (s & 24) | ((s ^ grp) & 7);
        *reinterpret_cast<uint4*>(&sA[(grp << 8) + (sp << 3)]) = v;
    }
    {
        uint4 o = gather_mean(hb, rp, col, n, l);
        int sp = (l & 24) | ((l ^ grp) & 7);
        *reinterpret_cast<uint4*>(&sA[(grp << 8) + (sp << 3)]) = o;
    }
    __syncthreads();

    const int lane = tid & 63;
    const int w = tid >> 6;
    const int rloc = lane & 15;
    const int q = lane >> 4;

    // ---- layer-2 MFMA (K=256) ----
    f32x4 acc[2];
    acc[0] = (f32x4){0.f, 0.f, 0.f, 0.f};
    acc[1] = (f32x4){0.f, 0.f, 0.f, 0.f};
#pragma unroll
    for (int kt = 0; kt < 8; ++kt) {
        int s = kt * 4 + q;
        int sp = (s & 24) | ((s ^ rloc) & 7);
        short8 a = *reinterpret_cast<const short8*>(&sA[(rloc << 8) + (sp << 3)]);
#pragma unroll
        for (int jj = 0; jj < 2; ++jj) {
            int jt = w * 2 + jj;
            short8 b = *reinterpret_cast<const short8*>(Wp2 + ((size_t)((kt * 8 + jt) * 64 + lane) << 3));
            acc[jj] = __builtin_amdgcn_mfma_f32_16x16x32_bf16(a, b, acc[jj], 0, 0, 0);
        }
    }

    // ---- epilogue 2: h2 = relu(acc + b2) + hb_self (from sA), write bf16 to sH ----
#pragma unroll
    for (int jj = 0; jj < 2; ++jj) {
        int j = (w * 2 + jj) * 16 + (lane & 15);
        float bj = b2[j];
        int sSelf = 16 + (j >> 3);
        int s = j >> 3;                               // h2 slot 0..15
#pragma unroll
        for (int reg = 0; reg < 4; ++reg) {
            int r = q * 4 + reg;
            int spSelf = (sSelf & 24) | ((sSelf ^ r) & 7);
            float hself = bf2f(sA[(r << 8) + (spSelf << 3) + (j & 7)]);
            float v = fmaxf(acc[jj][reg] + bj, 0.f) + hself;
            int sp = (s & 8) | ((s ^ r) & 7);
            sH[(r << 7) + (sp << 3) + (j & 7)] = f2bf(v);
        }
    }
    __syncthreads();

    // ---- layer-3 MFMA (K=128) ----
    acc[0] = (f32x4){0.f, 0.f, 0.f, 0.f};
    acc[1] = (f32x4){0.f, 0.f, 0.f, 0.f};
#pragma unroll
    for (int kt = 0; kt < 4; ++kt) {
        int s = kt * 4 + q;
        int sp = (s & 8) | ((s ^ rloc) & 7);
        short8 a = *reinterpret_cast<const short8*>(&sH[(rloc << 7) + (sp << 3)]);
#pragma unroll
        for (int jj = 0; jj < 2; ++jj) {
            int jt = w * 2 + jj;
            short8 b = *reinterpret_cast<const short8*>(Wp3 + ((size_t)((kt * 8 + jt) * 64 + lane) << 3));
            acc[jj] = __builtin_amdgcn_mfma_f32_16x16x32_bf16(a, b, acc[jj], 0, 0, 0);
        }
    }

    // ---- epilogue 3: jt<4 -> y3 bf16; jt>=4 -> out = z3 + b3 fp32 ----
#pragma unroll
    for (int jj = 0; jj < 2; ++jj) {
        int jt = w * 2 + jj;
        int j = jt * 16 + (lane & 15);
#pragma unroll
        for (int reg = 0; reg < 4; ++reg) {
            int nn = n0 + q * 4 + reg;
            if (nn < N) {
                if (jt < 4) {
                    y3[((size_t)nn << 6) + j] = f2bf(acc[jj][reg]);
                } else {
                    out[((size_t)nn << 6) + (j - 64)] = acc[jj][reg] + b3[j - 64];
                }
            }
        }
    }
}

// ---------------- gather3: out[n] += mean over edges of y3[col[e]] (64-wide rows) ----
__global__ __launch_bounds__(256) void gather3_kernel(
    const ushort* __restrict__ y3, const int* __restrict__ rp,
    const ushort* __restrict__ col, float* __restrict__ out, int N)
{
    int node = blockIdx.x * 32 + (threadIdx.x >> 3);
    if (node >= N) return;
    int l = threadIdx.x & 7;
    int beg = rp[node], end = rp[node + 1];
    float4 a0 = make_float4(0.f, 0.f, 0.f, 0.f);
    float4 a1 = make_float4(0.f, 0.f, 0.f, 0.f);

    int e = beg;
    for (; e + 8 <= end; e += 8) {
        uint4 v0 = *reinterpret_cast<const uint4*>(y3 + ((size_t)col[e]     << 6) + l * 8);
        uint4 v1 = *reinterpret_cast<const uint4*>(y3 + ((size_t)col[e + 1] << 6) + l * 8);
        uint4 v2 = *reinterpret_cast<const uint4*>(y3 + ((size_t)col[e + 2] << 6) + l * 8);
        uint4 v3 = *reinterpret_cast<const uint4*>(y3 + ((size_t)col[e + 3] << 6) + l * 8);
        uint4 v4 = *reinterpret_cast<const uint4*>(y3 + ((size_t)col[e + 4] << 6) + l * 8);
        uint4 v5 = *reinterpret_cast<const uint4*>(y3 + ((size_t)col[e + 5] << 6) + l * 8);
        uint4 v6 = *reinterpret_cast<const uint4*>(y3 + ((size_t)col[e + 6] << 6) + l * 8);
        uint4 v7 = *reinterpret_cast<const uint4*>(y3 + ((size_t)col[e + 7] << 6) + l * 8);
        a0 += unpk_lo(v0); a1 += unpk_hi(v0);
        a0 += unpk_lo(v1); a1 += unpk_hi(v1);
        a0 += unpk_lo(v2); a1 += unpk_hi(v2);
        a0 += unpk_lo(v3); a1 += unpk_hi(v3);
        a0 += unpk_lo(v4); a1 += unpk_hi(v4);
        a0 += unpk_lo(v5); a1 += unpk_hi(v5);
        a0 += unpk_lo(v6); a1 += unpk_hi(v6);
        a0 += unpk_lo(v7); a1 += unpk_hi(v7);
    }
    if (e < end) {
        int last = end - 1;
        int c0 = col[e];
        int c1 = col[min(e + 1, last)];
        int c2 = col[min(e + 2, last)];
        int c3 = col[min(e + 3, last)];
        int c4 = col[min(e + 4, last)];
        int c5 = col[min(e + 5, last)];
        int c6 = col[min(e + 6, last)];
        int c7 = col[min(e + 7, last)];
        uint4 v0 = *reinterpret_cast<const uint4*>(y3 + ((size_t)c0 << 6) + l * 8);
        uint4 v1 = *reinterpret_cast<const uint4*>(y3 + ((size_t)c1 << 6) + l * 8);
        uint4 v2 = *reinterpret_cast<const uint4*>(y3 + ((size_t)c2 << 6) + l * 8);
        uint4 v3 = *reinterpret_cast<const uint4*>(y3 + ((size_t)c3 << 6) + l * 8);
        uint4 v4 = *reinterpret_cast<const uint4*>(y3 + ((size_t)c4 << 6) + l * 8);
        uint4 v5 = *reinterpret_cast<const uint4*>(y3 + ((size_t)c5 << 6) + l * 8);
        uint4 v6 = *reinterpret_cast<const uint4*>(y3 + ((size_t)c6 << 6) + l * 8);
        uint4 v7 = *reinterpret_cast<const uint4*>(y3 + ((size_t)c7 << 6) + l * 8);
        float m1 = (e + 1 <= last) ? 1.f : 0.f;
        float m2 = (e + 2 <= last) ? 1.f : 0.f;
        float m3 = (e + 3 <= last) ? 1.f : 0.f;
        float m4 = (e + 4 <= last) ? 1.f : 0.f;
        float m5 = (e + 5 <= last) ? 1.f : 0.f;
        float m6 = (e + 6 <= last) ? 1.f : 0.f;
        float m7 = (e + 7 <= last) ? 1.f : 0.f;
        a0 += unpk_lo(v0);      a1 += unpk_hi(v0);
        a0 += unpk_lo(v1) * m1; a1 += unpk_hi(v1) * m1;
        a0 += unpk_lo(v2) * m2; a1 += unpk_hi(v2) * m2;
        a0 += unpk_lo(v3) * m3; a1 += unpk_hi(v3) * m3;
        a0 += unpk_lo(v4) * m4; a1 += unpk_hi(v4) * m4;
        a0 += unpk_lo(v5) * m5; a1 += unpk_hi(v5) * m5;
        a0 += unpk_lo(v6) * m6; a1 += unpk_hi(v6) * m6;
        a0 += unpk_lo(v7) * m7; a1 += unpk_hi(v7) * m7;
    }

    int deg = end - beg;
    float inv = 1.0f / (float)(deg > 1 ? deg : 1);
    float* po = out + ((size_t)node << 6) + l * 8;
    float4 o0 = *reinterpret_cast<const float4*>(po);
    float4 o1 = *reinterpret_cast<const float4*>(po + 4);
    o0.x += a0.x * inv; o0.y += a0.y * inv; o0.z += a0.z * inv; o0.w += a0.w * inv;
    o1.x += a1.x * inv; o1.y += a1.y * inv; o1.z += a1.z * inv; o1.w += a1.w * inv;
    *reinterpret_cast<float4*>(po)     = o0;
    *reinterpret_cast<float4*>(po + 4) = o1;
}

extern "C" void kernel_launch(void* const* d_in, const int* in_sizes, int n_in,
                              void* d_out, int out_size, void* d_ws, size_t ws_size,
                              hipStream_t stream) {
    const float* x   = (const float*)d_in[0];
    const int*   ei1 = (const int*)d_in[1];
    const int*   ei2 = (const int*)d_in[2];
    const int*   ei3 = (const int*)d_in[3];
    const float* Wl1 = (const float*)d_in[4];
    const float* Wr1 = (const float*)d_in[5];
    const float* b1  = (const float*)d_in[6];
    const float* Wl2 = (const float*)d_in[7];
    const float* Wr2 = (const float*)d_in[8];
    const float* b2  = (const float*)d_in[9];
    const float* Wl3 = (const float*)d_in[10];
    const float* Wr3 = (const float*)d_in[11];
    const float* b3  = (const float*)d_in[12];
    float* out = (float*)d_out;

    const int N = in_sizes[0] / FDIM;   // 50000
    const int E = in_sizes[1] / 2;      // 800000
    const int NB = (N + 511) >> 9;      // 98 buckets of 512 nodes

    auto al = [](size_t v) { return (v + 255) & ~(size_t)255; };
    char* ws = (char*)d_ws;
    ushort* xb   = (ushort*)ws;   ws += al((size_t)N * FDIM * 2);
    ushort* hb   = (ushort*)ws;   ws += al((size_t)N * FDIM * 2);
    ushort* y3   = (ushort*)ws;   ws += al((size_t)N * 64 * 2);
    ushort* Wp1  = (ushort*)ws;   ws += al((size_t)8 * 8 * 64 * 8 * 2);
    ushort* Wp2  = (ushort*)ws;   ws += al((size_t)8 * 8 * 64 * 8 * 2);
    ushort* Wp3  = (ushort*)ws;   ws += al((size_t)4 * 8 * 64 * 8 * 2);
    int*     rowptr = (int*)ws;   ws += al((size_t)(3 * N + 1) * 4);
    int*     gCnt   = (int*)ws;   ws += al((size_t)(3 * NB) * 4);
    unsigned* binned = (unsigned*)ws; ws += al((size_t)3 * NB * CAPB * 4);
    ushort*  colu   = (ushort*)ws;

    const int bpg = (E + 4095) / 4096;
    const int n4  = N * FDIM / 4;
    const int fusedBlocks   = (N + 15) / 16;
    const int gather3Blocks = (N + 31) / 32;

    // pack weights + zero gCnt (stream-ordered before binconv's atomics)
    pack_kernel<<<40, 256, 0, stream>>>(
        gCnt, 3 * NB, Wl1, Wr1, Wl2, Wr2, Wl3, Wr3, Wp1, Wp2, Wp3);

    // bin (blocks 0..3*bpg-1) overlapped with x->bf16 convert (remaining blocks)
    binconv_kernel<<<3 * bpg + (n4 + 255) / 256, 256, 0, stream>>>(
        ei1, ei2, ei3, gCnt, binned, E, NB, bpg, x, xb, n4);

    // per-bucket CSR fill (self-scanning)
    fill2_kernel<<<3 * NB, 256, 0, stream>>>(binned, gCnt, rowptr, colu, N, NB);

    // fused layer 1: gather + GEMM
    fused_l1<<<fusedBlocks, 256, 0, stream>>>(xb, rowptr, colu, Wp1, b1, hb, N);

    // fused layers 2+3: gather + GEMM2 + GEMM3 (h2 via LDS)
    fused_l23<<<fusedBlocks, 256, 0, stream>>>(
        hb, rowptr + N, colu, Wp2, b2, Wp3, b3, y3, out, N);

    // out += mean3(y3)
    gather3_kernel<<<gather3Blocks, 256, 0, stream>>>(y3, rowptr + 2 * N, colu, out, N);
}